// Round 15
// baseline (606.486 us; speedup 1.0000x reference)
//
#include <hip/hip_runtime.h>

#define H 1024
#define T_STEPS 64
#define S_MEM 512
#define VA 30
#define VW 30000

typedef unsigned long long u64;
typedef __attribute__((ext_vector_type(8))) short short8;
typedef __attribute__((ext_vector_type(4))) float f32x4;

__device__ __forceinline__ float sigmf(float x) { return 1.f / (1.f + expf(-x)); }
__device__ __forceinline__ unsigned short f2bf(float f) {
  unsigned u = __float_as_uint(f);
  return (unsigned short)((u + 0x7FFFu + ((u >> 16) & 1u)) >> 16);
}
__device__ __forceinline__ short8 ldcvt8(const float* p) {
  float4 f0 = *(const float4*)p;
  float4 f1 = *(const float4*)(p + 4);
  short8 r;
  r[0] = (short)f2bf(f0.x); r[1] = (short)f2bf(f0.y);
  r[2] = (short)f2bf(f0.z); r[3] = (short)f2bf(f0.w);
  r[4] = (short)f2bf(f1.x); r[5] = (short)f2bf(f1.y);
  r[6] = (short)f2bf(f1.z); r[7] = (short)f2bf(f1.w);
  return r;
}
__device__ __forceinline__ void stage_sw(float* S, int nn, int km, float4 v) {
  int c2 = ((nn >> 2) ^ km) & 15, p = nn & 3;
  S[(km * 4 + 0) * 64 + c2 * 4 + p] = v.x;
  S[(km * 4 + 1) * 64 + c2 * 4 + p] = v.y;
  S[(km * 4 + 2) * 64 + c2 * 4 + p] = v.z;
  S[(km * 4 + 3) * 64 + c2 * 4 + p] = v.w;
}
__device__ __forceinline__ void mm_inner(const float* As, const float* Bs,
                                         int ridx, int cidx, float (&acc)[4][4]) {
  const float4* As4 = (const float4*)As;
  const float4* Bs4 = (const float4*)Bs;
  __syncthreads();
#pragma unroll 8
  for (int kk = 0; kk < 64; ++kk) {
    int sw = kk >> 2;
    float4 a4 = As4[kk * 16 + ((ridx ^ sw) & 15)];
    float4 b4 = Bs4[kk * 16 + ((cidx ^ sw) & 15)];
    float av[4] = {a4.x, a4.y, a4.z, a4.w};
    float bv[4] = {b4.x, b4.y, b4.z, b4.w};
#pragma unroll
    for (int i = 0; i < 4; ++i)
#pragma unroll
      for (int j = 0; j < 4; ++j) acc[i][j] += av[i] * bv[j];
  }
  __syncthreads();
}
// MALL-coherent float4 store/load (intra-kernel cross-block data)
__device__ __forceinline__ void st4a(float* p, float4 v) {
  u64 lo = ((u64)__float_as_uint(v.y) << 32) | __float_as_uint(v.x);
  u64 hi = ((u64)__float_as_uint(v.w) << 32) | __float_as_uint(v.z);
  __hip_atomic_store((u64*)p, lo, __ATOMIC_RELAXED, __HIP_MEMORY_SCOPE_AGENT);
  __hip_atomic_store(((u64*)p) + 1, hi, __ATOMIC_RELAXED, __HIP_MEMORY_SCOPE_AGENT);
}
__device__ __forceinline__ float4 ld4a(const float* p) {
  u64 lo = __hip_atomic_load((const u64*)p, __ATOMIC_RELAXED, __HIP_MEMORY_SCOPE_AGENT);
  u64 hi = __hip_atomic_load(((const u64*)p) + 1, __ATOMIC_RELAXED, __HIP_MEMORY_SCOPE_AGENT);
  return make_float4(__uint_as_float((unsigned)lo), __uint_as_float((unsigned)(lo >> 32)),
                     __uint_as_float((unsigned)hi), __uint_as_float((unsigned)(hi >> 32)));
}

// ================= k_head: init + xg GEMM (embeddings gathered in staging) =================
__global__ __launch_bounds__(256) void k_head(
    const int* __restrict__ actions, const int* __restrict__ words,
    const float* __restrict__ act_emb, const float* __restrict__ word_emb,
    const float* __restrict__ Wih_t, const float* __restrict__ Wih_a,
    float* __restrict__ Pxg_t, float* __restrict__ Pxg_a,
    float* __restrict__ fin, u64* __restrict__ htag, int* __restrict__ m2ctr) {
  int x = blockIdx.x, tid = threadIdx.x, y = blockIdx.y, z = blockIdx.z;
  if (x == 64) {
    int bi = y * 2 + z;
    uint4* hq = (uint4*)(htag) + (size_t)bi * 16384;
    uint4 zz = make_uint4(0, 0, 0, 0);
    for (int i = tid; i < 16384; i += 256) hq[i] = zz;
    if (bi == 0)
      for (int i = tid; i < 3072; i += 256) fin[i] = 0.f;   // term/act/stack at t=0
    if (bi == 1) {
      for (int j = tid; j < 63 * 1024; j += 256) {
        int t = j >> 10, i2 = j & 1023;
        fin[(size_t)(t + 1) * 4096 + 2048 + i2] = word_emb[(size_t)words[t] * 1024 + i2];
      }
    }
    if (bi == 2 && tid < 8) m2ctr[tid] = 0;
    return;
  }
  __shared__ __align__(16) float As[4096], Bs[4096];
  const int* idxs = z ? actions : words;
  const float* emb = z ? act_emb : word_emb;
  const float* B = z ? Wih_a : Wih_t;
  float* Pp = z ? Pxg_a : Pxg_t;
  int cidx = tid & 15, ridx = tid >> 4;
  int n0 = x * 64, kbeg = y * 512;
  float acc[4][4] = {};
  for (int k0 = kbeg; k0 < kbeg + 512; k0 += 64) {
#pragma unroll
    for (int i = 0; i < 4; ++i) {
      int f = tid + i * 256, rr = f >> 4, km = f & 15;
      float4 v = *(const float4*)&emb[(size_t)idxs[rr] * 1024 + k0 + km * 4];
      stage_sw(As, rr, km, v);
    }
#pragma unroll
    for (int i = 0; i < 4; ++i) {
      int f = tid + i * 256, nn = f >> 4, km = f & 15;
      float4 v = *(const float4*)&B[(size_t)(n0 + nn) * 1024 + k0 + km * 4];
      stage_sw(Bs, nn, km, v);
    }
    mm_inner(As, Bs, ridx, cidx, acc);
  }
  int gcol = n0 + cidx * 4;
  float* P = Pp + (size_t)y * 262144;
#pragma unroll
  for (int i = 0; i < 4; ++i) {
    int row = ridx * 4 + i;
    *(float4*)&P[(size_t)row * 4096 + gcol] =
        make_float4(acc[i][0], acc[i][1], acc[i][2], acc[i][3]);
  }
}

// ======= mega kernel: blocks 0-255 recur; 256-511 M2=mem^T mem; 512-703 W'T=M2@Wq;
//         block 704: bq2 = bq@M2. Prep runs on pipes recur leaves idle. =======
__global__ __launch_bounds__(256, 1) void k_recur(
    const float* __restrict__ Whh_term, const float* __restrict__ Whh_act,
    const float* __restrict__ Pxg_term, const float* __restrict__ Pxg_act,
    const float* __restrict__ bih_t, const float* __restrict__ bhh_t,
    const float* __restrict__ bih_a, const float* __restrict__ bhh_a,
    float* __restrict__ fin, u64* __restrict__ htag,
    const float* __restrict__ memory, const float* __restrict__ Wq,
    const float* __restrict__ bq, float* __restrict__ M2,
    float* __restrict__ WpT, float* __restrict__ bq2, int* __restrict__ m2ctr) {
  __shared__ float hs[2][32 * 36];
  __shared__ float xgs[63 * 32];
  __shared__ __align__(16) float As[4096], Bs[4096];
  int b = blockIdx.x, tid = threadIdx.x;
  int cidx = tid & 15, ridx = tid >> 4;

  if (b >= 256) {
    if (b < 512) {
      // ---- M2 tile (i0,j0): M2[i,j] = sum_s mem[s,i] mem[s,j] ----
      int idx = b - 256;
      int i0 = (idx >> 4) * 64, j0 = (idx & 15) * 64;
      float acc[4][4] = {};
      for (int k0 = 0; k0 < 512; k0 += 64) {
#pragma unroll
        for (int i = 0; i < 4; ++i) {
          int f = tid + i * 256, kr = f >> 4, nq = f & 15;
          float4 v = *(const float4*)&memory[(size_t)(k0 + kr) * 1024 + i0 + nq * 4];
          ((float4*)As)[kr * 16 + ((nq ^ (kr >> 2)) & 15)] = v;
        }
#pragma unroll
        for (int i = 0; i < 4; ++i) {
          int f = tid + i * 256, kr = f >> 4, nq = f & 15;
          float4 v = *(const float4*)&memory[(size_t)(k0 + kr) * 1024 + j0 + nq * 4];
          ((float4*)Bs)[kr * 16 + ((nq ^ (kr >> 2)) & 15)] = v;
        }
        mm_inner(As, Bs, ridx, cidx, acc);
      }
      int gcol = j0 + cidx * 4;
#pragma unroll
      for (int i = 0; i < 4; ++i)
        st4a(&M2[(size_t)(i0 + ridx * 4 + i) * 1024 + gcol],
             make_float4(acc[i][0], acc[i][1], acc[i][2], acc[i][3]));
      asm volatile("s_waitcnt vmcnt(0)" ::: "memory");
      __syncthreads();
      if (tid == 0)
        __hip_atomic_fetch_add(&m2ctr[0], 1, __ATOMIC_RELAXED, __HIP_MEMORY_SCOPE_AGENT);
      return;
    }
    // wait for M2 complete
    if (tid == 0) {
      while (__hip_atomic_load(&m2ctr[0], __ATOMIC_RELAXED, __HIP_MEMORY_SCOPE_AGENT) < 256)
        __builtin_amdgcn_s_sleep(8);
    }
    __syncthreads();
    if (b == 704) {
      // ---- bq2[n] = sum_d bq[d] M2[n,d]  (M2 symmetric) ----
      for (int n = tid; n < 1024; n += 256) {
        float s = 0.f;
        for (int d = 0; d < 1024; d += 4) {
          float4 m = ld4a(&M2[(size_t)n * 1024 + d]);
          float4 bv = *(const float4*)&bq[d];
          s += m.x * bv.x + m.y * bv.y + m.z * bv.z + m.w * bv.w;
        }
        bq2[n] = s;
      }
      return;
    }
    // ---- W'T tiles: W'T[n,m] = sum_d M2[n,d] Wq[d,m]  (4 tiles per block) ----
    int idx = b - 512;
    for (int q = 0; q < 4; ++q) {
      int t = idx * 4 + q;                 // 768 tiles: 16 x 48
      int n0 = (t / 48) * 64, m0 = (t % 48) * 64;
      float acc[4][4] = {};
      for (int k0 = 0; k0 < 1024; k0 += 64) {
#pragma unroll
        for (int i = 0; i < 4; ++i) {
          int f = tid + i * 256, rr = f >> 4, km = f & 15;
          float4 v = ld4a(&M2[(size_t)(n0 + rr) * 1024 + k0 + km * 4]);
          stage_sw(As, rr, km, v);
        }
#pragma unroll
        for (int i = 0; i < 4; ++i) {
          int f = tid + i * 256, kr = f >> 4, nq = f & 15;
          float4 v = *(const float4*)&Wq[(size_t)(k0 + kr) * 3072 + m0 + nq * 4];
          ((float4*)Bs)[kr * 16 + ((nq ^ (kr >> 2)) & 15)] = v;
        }
        mm_inner(As, Bs, ridx, cidx, acc);
      }
      int gcol = m0 + cidx * 4;
#pragma unroll
      for (int i = 0; i < 4; ++i)
        *(float4*)&WpT[(size_t)(n0 + ridx * 4 + i) * 3072 + gcol] =
            make_float4(acc[i][0], acc[i][1], acc[i][2], acc[i][3]);
    }
    return;
  }

  // ---- recur path (R10/R12-proven) ----
  int lstm = b >> 7, k0 = (b & 127) * 8;
  const float* Whh = lstm ? Whh_act : Whh_term;
  const float* Pxg = lstm ? Pxg_act : Pxg_term;
  const float* bih = lstm ? bih_a : bih_t;
  const float* bhh = lstm ? bhh_a : bhh_t;
  int d = tid >> 5, p = tid & 31;

  float wreg[128];
#pragma unroll
  for (int g = 0; g < 4; ++g) {
    const float* wrow = Whh + (size_t)(g * 1024 + k0 + d) * 1024 + p * 32;
#pragma unroll
    for (int i = 0; i < 32; i += 4) {
      float4 v = *(const float4*)(wrow + i);
      wreg[g * 32 + i]     = v.x; wreg[g * 32 + i + 1] = v.y;
      wreg[g * 32 + i + 2] = v.z; wreg[g * 32 + i + 3] = v.w;
    }
  }
#pragma unroll
  for (int i = 0; i < 128; ++i) asm volatile("" : "+v"(wreg[i]));

  for (int i = tid; i < 63 * 32; i += 256) {
    int rr = i & 31, t2 = i >> 5;
    int row2 = (rr >> 3) * 1024 + k0 + (rr & 7);
    xgs[i] = Pxg[(size_t)t2 * 4096 + row2] + Pxg[262144 + (size_t)t2 * 4096 + row2] +
             bih[row2] + bhh[row2];
  }
  float c_loc = 0.f;

  for (int t = 0; t < 63; ++t) {
    float* hb = hs[t & 1];
    if (t > 0) {
      const u64* src = htag + (size_t)t * 2048 + lstm * 1024;
      u64 v0 = __hip_atomic_load(&src[tid], __ATOMIC_RELAXED, __HIP_MEMORY_SCOPE_AGENT);
      u64 v1 = __hip_atomic_load(&src[tid + 256], __ATOMIC_RELAXED, __HIP_MEMORY_SCOPE_AGENT);
      u64 v2 = __hip_atomic_load(&src[tid + 512], __ATOMIC_RELAXED, __HIP_MEMORY_SCOPE_AGENT);
      u64 v3 = __hip_atomic_load(&src[tid + 768], __ATOMIC_RELAXED, __HIP_MEMORY_SCOPE_AGENT);
      while ((unsigned)(v0 >> 32) != (unsigned)t) {
        __builtin_amdgcn_s_sleep(1);
        v0 = __hip_atomic_load(&src[tid], __ATOMIC_RELAXED, __HIP_MEMORY_SCOPE_AGENT);
      }
      while ((unsigned)(v1 >> 32) != (unsigned)t) {
        __builtin_amdgcn_s_sleep(1);
        v1 = __hip_atomic_load(&src[tid + 256], __ATOMIC_RELAXED, __HIP_MEMORY_SCOPE_AGENT);
      }
      while ((unsigned)(v2 >> 32) != (unsigned)t) {
        __builtin_amdgcn_s_sleep(1);
        v2 = __hip_atomic_load(&src[tid + 512], __ATOMIC_RELAXED, __HIP_MEMORY_SCOPE_AGENT);
      }
      while ((unsigned)(v3 >> 32) != (unsigned)t) {
        __builtin_amdgcn_s_sleep(1);
        v3 = __hip_atomic_load(&src[tid + 768], __ATOMIC_RELAXED, __HIP_MEMORY_SCOPE_AGENT);
      }
      hb[((tid) >> 5) * 36 + (tid & 31)]       = __uint_as_float((unsigned)v0);
      hb[((tid + 256) >> 5) * 36 + (tid & 31)] = __uint_as_float((unsigned)v1);
      hb[((tid + 512) >> 5) * 36 + (tid & 31)] = __uint_as_float((unsigned)v2);
      hb[((tid + 768) >> 5) * 36 + (tid & 31)] = __uint_as_float((unsigned)v3);
    } else {
#pragma unroll
      for (int j = 0; j < 4; ++j) {
        int idx = tid + j * 256;
        hb[(idx >> 5) * 36 + (idx & 31)] = 0.f;
      }
    }
    __syncthreads();

    const float* hp = hb + p * 36;
    float s0 = 0.f, s1 = 0.f, s2 = 0.f, s3 = 0.f;
#pragma unroll
    for (int i = 0; i < 32; i += 4) {
      float4 hv = *(const float4*)&hp[i];
      s0 += wreg[i] * hv.x + wreg[i + 1] * hv.y + wreg[i + 2] * hv.z + wreg[i + 3] * hv.w;
      s1 += wreg[32 + i] * hv.x + wreg[33 + i] * hv.y + wreg[34 + i] * hv.z + wreg[35 + i] * hv.w;
      s2 += wreg[64 + i] * hv.x + wreg[65 + i] * hv.y + wreg[66 + i] * hv.z + wreg[67 + i] * hv.w;
      s3 += wreg[96 + i] * hv.x + wreg[97 + i] * hv.y + wreg[98 + i] * hv.z + wreg[99 + i] * hv.w;
    }
#pragma unroll
    for (int m = 1; m <= 16; m <<= 1) {
      s0 += __shfl_xor(s0, m); s1 += __shfl_xor(s1, m);
      s2 += __shfl_xor(s2, m); s3 += __shfl_xor(s3, m);
    }
    if (p == 0) {
      float gi = s0 + xgs[t * 32 + d];
      float gf = s1 + xgs[t * 32 + 8 + d];
      float gg = s2 + xgs[t * 32 + 16 + d];
      float go = s3 + xgs[t * 32 + 24 + d];
      float c2 = sigmf(gf) * c_loc + sigmf(gi) * tanhf(gg);
      float h2 = sigmf(go) * tanhf(c2);
      c_loc = c2;
      fin[(size_t)(t + 1) * 4096 + lstm * 1024 + k0 + d] = h2;
      __hip_atomic_store(&htag[(size_t)(t + 1) * 2048 + lstm * 1024 + k0 + d],
                         (((u64)(t + 1)) << 32) | (u64)__float_as_uint(h2),
                         __ATOMIC_RELAXED, __HIP_MEMORY_SCOPE_AGENT);
    }
  }
}

// ---------------- fp32 GEMM partials: C[64,N] = A[64,K] * B^T  (used for ctx) ----------------
__global__ __launch_bounds__(256) void k_gemm64(
    const float* __restrict__ A, int lda,
    const float* __restrict__ B, int ldb,
    int N, int K, float* __restrict__ Ppart) {
  __shared__ __align__(16) float As[4096], Bs[4096];
  int tid = threadIdx.x, cidx = tid & 15, ridx = tid >> 4;
  int n0 = blockIdx.x * 64;
  int klen = K / gridDim.y, kbeg = blockIdx.y * klen;
  float acc[4][4] = {};
  for (int k0 = kbeg; k0 < kbeg + klen; k0 += 64) {
#pragma unroll
    for (int i = 0; i < 4; ++i) {
      int f = tid + i * 256, rr = f >> 4, km = f & 15;
      float4 v = *(const float4*)&A[(size_t)rr * lda + k0 + km * 4];
      stage_sw(As, rr, km, v);
    }
#pragma unroll
    for (int i = 0; i < 4; ++i) {
      int f = tid + i * 256, nn = f >> 4, km = f & 15;
      float4 v = *(const float4*)&B[(size_t)(n0 + nn) * ldb + k0 + km * 4];
      stage_sw(Bs, nn, km, v);
    }
    mm_inner(As, Bs, ridx, cidx, acc);
  }
  int gcol = n0 + cidx * 4;
  float* P = Ppart + (size_t)blockIdx.y * 64 * N;
#pragma unroll
  for (int i = 0; i < 4; ++i) {
    int row = ridx * 4 + i;
    *(float4*)&P[(size_t)row * N + gcol] =
        make_float4(acc[i][0], acc[i][1], acc[i][2], acc[i][3]);
  }
}

// ------- dual GEMM (ha/hw): A = [fin(0:3072) | sum8(Pc2)+bq2], z selects (B, P) -------
__global__ __launch_bounds__(256) void k_gemm_dual(
    const float* __restrict__ A0, int lda,
    const float* __restrict__ B0, const float* __restrict__ B1, int ldb,
    int N, int K, float* __restrict__ P0, float* __restrict__ P1,
    const float* __restrict__ Pc2, const float* __restrict__ bq2, int kb) {
  __shared__ __align__(16) float As[4096], Bs[4096];
  const float* B = blockIdx.z ? B1 : B0;
  float* Pp = blockIdx.z ? P1 : P0;
  int tid = threadIdx.x, cidx = tid & 15, ridx = tid >> 4;
  int n0 = blockIdx.x * 64;
  int klen = K / gridDim.y, kbeg = blockIdx.y * klen;
  float acc[4][4] = {};
  for (int k0 = kbeg; k0 < kbeg + klen; k0 += 64) {
#pragma unroll
    for (int i = 0; i < 4; ++i) {
      int f = tid + i * 256, rr = f >> 4, km = f & 15;
      float4 v;
      if (k0 >= kb) {
        int kc = k0 - kb + km * 4;
        float4 bb = *(const float4*)&bq2[kc];
        v = bb;
#pragma unroll
        for (int s = 0; s < 8; ++s) {
          float4 pp = *(const float4*)&Pc2[(size_t)s * 65536 + (size_t)rr * 1024 + kc];
          v.x += pp.x; v.y += pp.y; v.z += pp.z; v.w += pp.w;
        }
      } else {
        v = *(const float4*)&A0[(size_t)rr * lda + k0 + km * 4];
      }
      stage_sw(As, rr, km, v);
    }
#pragma unroll
    for (int i = 0; i < 4; ++i) {
      int f = tid + i * 256, nn = f >> 4, km = f & 15;
      float4 v = *(const float4*)&B[(size_t)(n0 + nn) * ldb + k0 + km * 4];
      stage_sw(Bs, nn, km, v);
    }
    mm_inner(As, Bs, ridx, cidx, acc);
  }
  int gcol = n0 + cidx * 4;
  float* P = Pp + (size_t)blockIdx.y * 64 * N;
#pragma unroll
  for (int i = 0; i < 4; ++i) {
    int row = ridx * 4 + i;
    *(float4*)&P[(size_t)row * N + gcol] =
        make_float4(acc[i][0], acc[i][1], acc[i][2], acc[i][3]);
  }
}

// ---------------- dual reduce + relu; bf16 copy of hw ----------------
__global__ __launch_bounds__(256) void k_reduce_dual(
    const float* __restrict__ P0, const float* __restrict__ P1, int S, int N,
    const float* __restrict__ ba0, const float* __restrict__ ba1,
    float* __restrict__ o0, float* __restrict__ o1, int relu,
    unsigned short* __restrict__ hwb_out) {
  const float* P = blockIdx.y ? P1 : P0;
  const float* bias = blockIdx.y ? ba1 : ba0;
  float* out = blockIdx.y ? o1 : o0;
  int q = blockIdx.x * 256 + threadIdx.x;
  int total = 64 * N / 4;
  if (q >= total) return;
  int e0 = q * 4;
  int col = e0 % N;
  float4 v = make_float4(0, 0, 0, 0);
  for (int s = 0; s < S; ++s) {
    float4 p = *(const float4*)&P[(size_t)s * 64 * N + e0];
    v.x += p.x; v.y += p.y; v.z += p.z; v.w += p.w;
  }
  float4 b = *(const float4*)&bias[col];
  v.x += b.x; v.y += b.y; v.z += b.z; v.w += b.w;
  if (relu) {
    v.x = fmaxf(v.x, 0.f); v.y = fmaxf(v.y, 0.f);
    v.z = fmaxf(v.z, 0.f); v.w = fmaxf(v.w, 0.f);
  }
  *(float4*)&out[e0] = v;
  if (blockIdx.y == 1 && hwb_out) {
    unsigned pk0 = (unsigned)f2bf(v.x) | ((unsigned)f2bf(v.y) << 16);
    unsigned pk1 = (unsigned)f2bf(v.z) | ((unsigned)f2bf(v.w) << 16);
    *(uint2*)&hwb_out[e0] = make_uint2(pk0, pk1);
  }
}

// ---------------- action logits ----------------
__global__ __launch_bounds__(256) void k_actlog(
    const float* __restrict__ ha, const float* __restrict__ Wa2,
    const float* __restrict__ ba2, float* __restrict__ out) {
  int t = blockIdx.x, tid = threadIdx.x;
  int v = tid >> 3, p = tid & 7;
  float sum = 0.f;
  if (v < VA) {
    const float* a  = ha + (size_t)t * 1024 + p * 128;
    const float* wr = Wa2 + (size_t)v * 1024 + p * 128;
#pragma unroll 8
    for (int i = 0; i < 128; i += 4) {
      float4 av = *(const float4*)(a + i);
      float4 wv = *(const float4*)(wr + i);
      sum += av.x * wv.x + av.y * wv.y + av.z * wv.z + av.w * wv.w;
    }
  }
  sum += __shfl_xor(sum, 1);
  sum += __shfl_xor(sum, 2);
  sum += __shfl_xor(sum, 4);
  if (p == 0 && v < VA) out[(size_t)t * VA + v] = sum + ba2[v];
}

// ---------------- word logits via bf16 MFMA (R12-proven) ----------------
__global__ __launch_bounds__(256) void k_word_mfma(
    const unsigned short* __restrict__ hwb, const float* __restrict__ Ww2,
    const float* __restrict__ bw2, float* __restrict__ outw) {
  int tid = threadIdx.x;
  int wv = tid >> 6, lane = tid & 63;
  int col = blockIdx.x * 64 + wv * 16 + (lane & 15);
  int colr = col < VW ? col : VW - 1;
  int kg = (lane >> 4) * 8;
  const float* brow = Ww2 + (size_t)colr * 1024 + kg;
  const unsigned short* arow = hwb + (size_t)(lane & 15) * 1024 + kg;
  f32x4 acc0 = {0.f, 0.f, 0.f, 0.f}, acc1 = acc0, acc2 = acc0, acc3 = acc0;

  short8 bf = ldcvt8(brow);
  short8 a0 = *(const short8*)(arow);
  short8 a1 = *(const short8*)(arow + 16 * 1024);
  short8 a2 = *(const short8*)(arow + 32 * 1024);
  short8 a3 = *(const short8*)(arow + 48 * 1024);
  for (int k0 = 0; k0 < 992; k0 += 32) {
    short8 bf_n = ldcvt8(brow + k0 + 32);
    short8 a0n = *(const short8*)(arow + k0 + 32);
    short8 a1n = *(const short8*)(arow + 16 * 1024 + k0 + 32);
    short8 a2n = *(const short8*)(arow + 32 * 1024 + k0 + 32);
    short8 a3n = *(const short8*)(arow + 48 * 1024 + k0 + 32);
    acc0 = __builtin_amdgcn_mfma_f32_16x16x32_bf16(a0, bf, acc0, 0, 0, 0);
    acc1 = __builtin_amdgcn_mfma_f32_16x16x32_bf16(a1, bf, acc1, 0, 0, 0);
    acc2 = __builtin_amdgcn_mfma_f32_16x16x32_bf16(a2, bf, acc2, 0, 0, 0);
    acc3 = __builtin_amdgcn_mfma_f32_16x16x32_bf16(a3, bf, acc3, 0, 0, 0);
    bf = bf_n; a0 = a0n; a1 = a1n; a2 = a2n; a3 = a3n;
  }
  acc0 = __builtin_amdgcn_mfma_f32_16x16x32_bf16(a0, bf, acc0, 0, 0, 0);
  acc1 = __builtin_amdgcn_mfma_f32_16x16x32_bf16(a1, bf, acc1, 0, 0, 0);
  acc2 = __builtin_amdgcn_mfma_f32_16x16x32_bf16(a2, bf, acc2, 0, 0, 0);
  acc3 = __builtin_amdgcn_mfma_f32_16x16x32_bf16(a3, bf, acc3, 0, 0, 0);

  if (col < VW) {
    float bias = bw2[col];
    int r0 = (lane >> 4) * 4;
#pragma unroll
    for (int j = 0; j < 4; ++j) {
      outw[(size_t)(r0 + j) * VW + col]      = acc0[j] + bias;
      outw[(size_t)(16 + r0 + j) * VW + col] = acc1[j] + bias;
      outw[(size_t)(32 + r0 + j) * VW + col] = acc2[j] + bias;
      outw[(size_t)(48 + r0 + j) * VW + col] = acc3[j] + bias;
    }
  }
}

extern "C" void kernel_launch(void* const* d_in, const int* in_sizes, int n_in,
                              void* d_out, int out_size, void* d_ws, size_t ws_size,
                              hipStream_t stream) {
  const float* memory   = (const float*)d_in[0];
  const int*   actions  = (const int*)d_in[1];
  const int*   words    = (const int*)d_in[2];
  const float* term_Wih = (const float*)d_in[3];
  const float* term_Whh = (const float*)d_in[4];
  const float* term_bih = (const float*)d_in[5];
  const float* term_bhh = (const float*)d_in[6];
  const float* act_Wih  = (const float*)d_in[7];
  const float* act_Whh  = (const float*)d_in[8];
  const float* act_bih  = (const float*)d_in[9];
  const float* act_bhh  = (const float*)d_in[10];
  const float* Wq  = (const float*)d_in[11];
  const float* bq  = (const float*)d_in[12];
  const float* Wa1 = (const float*)d_in[13];
  const float* ba1 = (const float*)d_in[14];
  const float* Wa2 = (const float*)d_in[15];
  const float* ba2 = (const float*)d_in[16];
  const float* Ww1 = (const float*)d_in[17];
  const float* bw1 = (const float*)d_in[18];
  const float* Ww2 = (const float*)d_in[19];
  const float* bw2 = (const float*)d_in[20];
  const float* act_emb  = (const float*)d_in[21];
  const float* word_emb = (const float*)d_in[22];
  float* out = (float*)d_out;

  // workspace (floats), lifetimes overlapped
  float* w     = (float*)d_ws;
  float* fin   = w;                       // 262144
  u64*   htag  = (u64*)(w + 262144);      // 131072 u64
  int*   m2ctr = (int*)(w + 524288);      // 8 ints (1024-float slot)
  float* Pxg_t = w + 525312;              // 524288
  float* Pxg_a = w + 1049600;             // 524288
  float* M2    = w + 1573888;             // 1048576
  float* WpT   = w + 2622464;             // 3145728
  float* bq2   = w + 5768192;             // 1024
  // post-recur overlays:
  float* Pc2   = Pxg_t;                   // 524288 (ctx partials)
  float* Pha   = Pxg_a;                   // 524288
  float* Phw   = M2;                      // 524288 (M2 dead after recur)
  float* ha    = w + 525312 + 0;          // reuse Pc2 region after hahw
  float* hw    = w + 525312 + 65536;
  unsigned short* hwb = (unsigned short*)(w + 525312 + 131072);

  k_head<<<dim3(65, 2, 2), 256, 0, stream>>>(
      actions, words, act_emb, word_emb, term_Wih, act_Wih,
      Pxg_t, Pxg_a, fin, htag, m2ctr);

  // recur + hidden precompute (M2, W'T, bq2)
  k_recur<<<705, 256, 0, stream>>>(
      term_Whh, act_Whh, Pxg_t, Pxg_a,
      term_bih, term_bhh, act_bih, act_bhh, fin, htag,
      memory, Wq, bq, M2, WpT, bq2, m2ctr);

  // ctx partials: states @ W'T^T  (K=3072, splitk=8)  [q & attn eliminated]
  k_gemm64<<<dim3(16, 8), 256, 0, stream>>>(fin, 4096, WpT, 3072, 1024, 3072, Pc2);

  // ha/hw partials: A = [fin(0:3072) | sum8(Pc2)+bq2]
  k_gemm_dual<<<dim3(16, 8, 2), 256, 0, stream>>>(
      fin, 4096, Wa1, Ww1, 4096, 1024, 4096, Pha, Phw, Pc2, bq2, 3072);
  k_reduce_dual<<<dim3(64, 2), 256, 0, stream>>>(
      Pha, Phw, 8, 1024, ba1, bw1, ha, hw, 1, hwb);

  k_actlog<<<64, 256, 0, stream>>>(ha, Wa2, ba2, out);
  k_word_mfma<<<469, 256, 0, stream>>>(hwb, Ww2, bw2, out + 1920);
}

// Round 16
// 457.831 us; speedup vs baseline: 1.3247x; 1.3247x over previous
//
#include <hip/hip_runtime.h>

#define H 1024
#define T_STEPS 64
#define S_MEM 512
#define VA 30
#define VW 30000
#define VWPAD 30016

typedef unsigned long long u64;
typedef __attribute__((ext_vector_type(8))) short short8;
typedef __attribute__((ext_vector_type(4))) float f32x4;

__device__ __forceinline__ float sigmf(float x) { return 1.f / (1.f + expf(-x)); }
__device__ __forceinline__ unsigned short f2bf(float f) {
  unsigned u = __float_as_uint(f);
  return (unsigned short)((u + 0x7FFFu + ((u >> 16) & 1u)) >> 16);
}
__device__ __forceinline__ short8 ldcvt8(const float* p) {
  float4 f0 = *(const float4*)p;
  float4 f1 = *(const float4*)(p + 4);
  short8 r;
  r[0] = (short)f2bf(f0.x); r[1] = (short)f2bf(f0.y);
  r[2] = (short)f2bf(f0.z); r[3] = (short)f2bf(f0.w);
  r[4] = (short)f2bf(f1.x); r[5] = (short)f2bf(f1.y);
  r[6] = (short)f2bf(f1.z); r[7] = (short)f2bf(f1.w);
  return r;
}

// ---------------- init: gather embeddings, stack slices, zero states + htag ----------------
__global__ __launch_bounds__(256) void k_init(
    const int* __restrict__ actions, const int* __restrict__ words,
    const float* __restrict__ act_emb, const float* __restrict__ word_emb,
    float* __restrict__ X_term, float* __restrict__ X_act,
    float* __restrict__ fin, u64* __restrict__ htag) {
  int b = blockIdx.x, tid = threadIdx.x;
  if (b < T_STEPS) {
    int wi = words[b], ai = actions[b];
    for (int i = tid; i < H; i += 256) {
      float we = word_emb[(size_t)wi * H + i];
      X_term[b * H + i] = we;
      X_act[b * H + i]  = act_emb[(size_t)ai * H + i];
      if (b + 1 < T_STEPS) fin[(size_t)(b + 1) * 4096 + 2048 + i] = we;  // stack_h[t+1]=w_e[t]
    }
    if (b == 0)
      for (int i = tid; i < H; i += 256) fin[2048 + i] = 0.f;            // stack_h[0]=0
  } else if (b == T_STEPS) {
    for (int i = tid; i < H; i += 256) { fin[i] = 0.f; fin[H + i] = 0.f; }
  } else {
    // zero all tag words so stale tags from a prior replay can't match
    for (int i = (b - 65) * 256 + tid; i < 64 * 2048; i += 64 * 256) htag[i] = 0ull;
  }
}

// ---------------- fp32 GEMM: C[64,N] = A[64,K] * B^T partials (used for q) ----------------
__global__ __launch_bounds__(256) void k_gemm64(
    const float* __restrict__ A, int lda,
    const float* __restrict__ B, int ldb,
    int N, int K, float* __restrict__ Ppart) {
  __shared__ __align__(16) float As[64 * 64];
  __shared__ __align__(16) float Bs[64 * 64];
  const float4* As4 = (const float4*)As;
  const float4* Bs4 = (const float4*)Bs;
  int tid = threadIdx.x;
  int cidx = tid & 15;
  int ridx = tid >> 4;
  int n0 = blockIdx.x * 64;
  int klen = K / gridDim.y;
  int kbeg = blockIdx.y * klen;
  float acc[4][4] = {};

  for (int k0 = kbeg; k0 < kbeg + klen; k0 += 64) {
#pragma unroll
    for (int i = 0; i < 4; ++i) {
      int f = tid + i * 256;
      int rr = f >> 4, km = f & 15;
      float4 v = *(const float4*)&A[(size_t)rr * lda + k0 + km * 4];
      int c2 = ((rr >> 2) ^ km) & 15, p = rr & 3;
      As[(km * 4 + 0) * 64 + c2 * 4 + p] = v.x;
      As[(km * 4 + 1) * 64 + c2 * 4 + p] = v.y;
      As[(km * 4 + 2) * 64 + c2 * 4 + p] = v.z;
      As[(km * 4 + 3) * 64 + c2 * 4 + p] = v.w;
    }
#pragma unroll
    for (int i = 0; i < 4; ++i) {
      int f = tid + i * 256;
      int nn = f >> 4, km = f & 15;
      int gn = n0 + nn;
      float4 v = make_float4(0.f, 0.f, 0.f, 0.f);
      if (gn < N) v = *(const float4*)&B[(size_t)gn * ldb + k0 + km * 4];
      int c2 = ((nn >> 2) ^ km) & 15, p = nn & 3;
      Bs[(km * 4 + 0) * 64 + c2 * 4 + p] = v.x;
      Bs[(km * 4 + 1) * 64 + c2 * 4 + p] = v.y;
      Bs[(km * 4 + 2) * 64 + c2 * 4 + p] = v.z;
      Bs[(km * 4 + 3) * 64 + c2 * 4 + p] = v.w;
    }
    __syncthreads();
#pragma unroll 8
    for (int kk = 0; kk < 64; ++kk) {
      int sw = kk >> 2;
      float4 a4 = As4[kk * 16 + ((ridx ^ sw) & 15)];
      float4 b4 = Bs4[kk * 16 + ((cidx ^ sw) & 15)];
      float av[4] = {a4.x, a4.y, a4.z, a4.w};
      float bv[4] = {b4.x, b4.y, b4.z, b4.w};
#pragma unroll
      for (int i = 0; i < 4; ++i)
#pragma unroll
        for (int j = 0; j < 4; ++j) acc[i][j] += av[i] * bv[j];
    }
    __syncthreads();
  }

  int gcol = n0 + cidx * 4;
  float* P = Ppart + (size_t)blockIdx.y * 64 * N;
  if (gcol < N) {
#pragma unroll
    for (int i = 0; i < 4; ++i) {
      int row = ridx * 4 + i;
      *(float4*)&P[(size_t)row * N + gcol] =
          make_float4(acc[i][0], acc[i][1], acc[i][2], acc[i][3]);
    }
  }
}

// ---------------- dual GEMM (BT=true, partials), z selects (A,B,P). If k0>=kb, A
// is staged as APc[0]+APc[1] (split-K partial sum of a previous GEMM). ----------------
__global__ __launch_bounds__(256) void k_gemm_dual(
    const float* __restrict__ A0, const float* __restrict__ A1, int lda,
    const float* __restrict__ B0, const float* __restrict__ B1, int ldb,
    int N, int K, float* __restrict__ P0, float* __restrict__ P1,
    const float* __restrict__ APc, int kb) {
  __shared__ __align__(16) float As[64 * 64];
  __shared__ __align__(16) float Bs[64 * 64];
  const float4* As4 = (const float4*)As;
  const float4* Bs4 = (const float4*)Bs;
  const float* A = blockIdx.z ? A1 : A0;
  const float* B = blockIdx.z ? B1 : B0;
  float* Pp = blockIdx.z ? P1 : P0;
  int tid = threadIdx.x;
  int cidx = tid & 15;
  int ridx = tid >> 4;
  int n0 = blockIdx.x * 64;
  int klen = K / gridDim.y;
  int kbeg = blockIdx.y * klen;
  float acc[4][4] = {};

  for (int k0 = kbeg; k0 < kbeg + klen; k0 += 64) {
#pragma unroll
    for (int i = 0; i < 4; ++i) {
      int f = tid + i * 256;
      int rr = f >> 4, km = f & 15;
      float4 v;
      if (k0 >= kb) {
        int kc = k0 - kb + km * 4;
        float4 a = *(const float4*)&APc[(size_t)rr * 1024 + kc];
        float4 c = *(const float4*)&APc[65536 + (size_t)rr * 1024 + kc];
        v = make_float4(a.x + c.x, a.y + c.y, a.z + c.z, a.w + c.w);
      } else {
        v = *(const float4*)&A[(size_t)rr * lda + k0 + km * 4];
      }
      int c2 = ((rr >> 2) ^ km) & 15, p = rr & 3;
      As[(km * 4 + 0) * 64 + c2 * 4 + p] = v.x;
      As[(km * 4 + 1) * 64 + c2 * 4 + p] = v.y;
      As[(km * 4 + 2) * 64 + c2 * 4 + p] = v.z;
      As[(km * 4 + 3) * 64 + c2 * 4 + p] = v.w;
    }
#pragma unroll
    for (int i = 0; i < 4; ++i) {
      int f = tid + i * 256;
      int nn = f >> 4, km = f & 15;
      int gn = n0 + nn;
      float4 v = make_float4(0.f, 0.f, 0.f, 0.f);
      if (gn < N) v = *(const float4*)&B[(size_t)gn * ldb + k0 + km * 4];
      int c2 = ((nn >> 2) ^ km) & 15, p = nn & 3;
      Bs[(km * 4 + 0) * 64 + c2 * 4 + p] = v.x;
      Bs[(km * 4 + 1) * 64 + c2 * 4 + p] = v.y;
      Bs[(km * 4 + 2) * 64 + c2 * 4 + p] = v.z;
      Bs[(km * 4 + 3) * 64 + c2 * 4 + p] = v.w;
    }
    __syncthreads();
#pragma unroll 8
    for (int kk = 0; kk < 64; ++kk) {
      int sw = kk >> 2;
      float4 a4 = As4[kk * 16 + ((ridx ^ sw) & 15)];
      float4 b4 = Bs4[kk * 16 + ((cidx ^ sw) & 15)];
      float av[4] = {a4.x, a4.y, a4.z, a4.w};
      float bv[4] = {b4.x, b4.y, b4.z, b4.w};
#pragma unroll
      for (int i = 0; i < 4; ++i)
#pragma unroll
        for (int j = 0; j < 4; ++j) acc[i][j] += av[i] * bv[j];
    }
    __syncthreads();
  }
  int gcol = n0 + cidx * 4;
  float* P = Pp + (size_t)blockIdx.y * 64 * N;
  if (gcol < N) {
#pragma unroll
    for (int i = 0; i < 4; ++i) {
      int row = ridx * 4 + i;
      *(float4*)&P[(size_t)row * N + gcol] =
          make_float4(acc[i][0], acc[i][1], acc[i][2], acc[i][3]);
    }
  }
}

// ---------------- attn GEMM: attn[64,512] partials; A = sum8(Pq) + bq ----------------
__global__ __launch_bounds__(256) void k_attn(
    const float* __restrict__ Pq, const float* __restrict__ bq,
    const float* __restrict__ mem, float* __restrict__ Pa) {
  __shared__ __align__(16) float As[64 * 64];
  __shared__ __align__(16) float Bs[64 * 64];
  const float4* As4 = (const float4*)As;
  const float4* Bs4 = (const float4*)Bs;
  int tid = threadIdx.x;
  int cidx = tid & 15;
  int ridx = tid >> 4;
  int n0 = blockIdx.x * 64;
  int kbeg = blockIdx.y * 128;   // splitk=8 over K=1024
  float acc[4][4] = {};

  for (int k0 = kbeg; k0 < kbeg + 128; k0 += 64) {
#pragma unroll
    for (int i = 0; i < 4; ++i) {
      int f = tid + i * 256;
      int rr = f >> 4, km = f & 15;
      int col = k0 + km * 4;
      float4 v = *(const float4*)&bq[col];
#pragma unroll
      for (int s = 0; s < 8; ++s) {
        float4 p = *(const float4*)&Pq[(size_t)s * 65536 + (size_t)rr * 1024 + col];
        v.x += p.x; v.y += p.y; v.z += p.z; v.w += p.w;
      }
      int c2 = ((rr >> 2) ^ km) & 15, p = rr & 3;
      As[(km * 4 + 0) * 64 + c2 * 4 + p] = v.x;
      As[(km * 4 + 1) * 64 + c2 * 4 + p] = v.y;
      As[(km * 4 + 2) * 64 + c2 * 4 + p] = v.z;
      As[(km * 4 + 3) * 64 + c2 * 4 + p] = v.w;
    }
#pragma unroll
    for (int i = 0; i < 4; ++i) {
      int f = tid + i * 256;
      int nn = f >> 4, km = f & 15;
      float4 v = *(const float4*)&mem[(size_t)(n0 + nn) * 1024 + k0 + km * 4];
      int c2 = ((nn >> 2) ^ km) & 15, p = nn & 3;
      Bs[(km * 4 + 0) * 64 + c2 * 4 + p] = v.x;
      Bs[(km * 4 + 1) * 64 + c2 * 4 + p] = v.y;
      Bs[(km * 4 + 2) * 64 + c2 * 4 + p] = v.z;
      Bs[(km * 4 + 3) * 64 + c2 * 4 + p] = v.w;
    }
    __syncthreads();
#pragma unroll 8
    for (int kk = 0; kk < 64; ++kk) {
      int sw = kk >> 2;
      float4 a4 = As4[kk * 16 + ((ridx ^ sw) & 15)];
      float4 b4 = Bs4[kk * 16 + ((cidx ^ sw) & 15)];
      float av[4] = {a4.x, a4.y, a4.z, a4.w};
      float bv[4] = {b4.x, b4.y, b4.z, b4.w};
#pragma unroll
      for (int i = 0; i < 4; ++i)
#pragma unroll
        for (int j = 0; j < 4; ++j) acc[i][j] += av[i] * bv[j];
    }
    __syncthreads();
  }
  int gcol = n0 + cidx * 4;
  float* P = Pa + (size_t)blockIdx.y * 64 * 512;
#pragma unroll
  for (int i = 0; i < 4; ++i) {
    int row = ridx * 4 + i;
    *(float4*)&P[(size_t)row * 512 + gcol] =
        make_float4(acc[i][0], acc[i][1], acc[i][2], acc[i][3]);
  }
}

// ---------------- ctx GEMM: ctx[64,1024] partials; A = sum8(Pa) ----------------
__global__ __launch_bounds__(256) void k_ctx(
    const float* __restrict__ Pa, const float* __restrict__ mem,
    float* __restrict__ Pc) {
  __shared__ __align__(16) float As[64 * 64];
  __shared__ __align__(16) float Bs[64 * 64];
  const float4* As4 = (const float4*)As;
  const float4* Bs4 = (const float4*)Bs;
  int tid = threadIdx.x;
  int cidx = tid & 15;
  int ridx = tid >> 4;
  int n0 = blockIdx.x * 64;
  int kbeg = blockIdx.y * 256;   // splitk=2 over K=512
  float acc[4][4] = {};

  for (int k0 = kbeg; k0 < kbeg + 256; k0 += 64) {
#pragma unroll
    for (int i = 0; i < 4; ++i) {
      int f = tid + i * 256;
      int rr = f >> 4, km = f & 15;
      int col = k0 + km * 4;
      float4 v = make_float4(0.f, 0.f, 0.f, 0.f);
#pragma unroll
      for (int s = 0; s < 8; ++s) {
        float4 p = *(const float4*)&Pa[(size_t)s * 32768 + (size_t)rr * 512 + col];
        v.x += p.x; v.y += p.y; v.z += p.z; v.w += p.w;
      }
      int c2 = ((rr >> 2) ^ km) & 15, p = rr & 3;
      As[(km * 4 + 0) * 64 + c2 * 4 + p] = v.x;
      As[(km * 4 + 1) * 64 + c2 * 4 + p] = v.y;
      As[(km * 4 + 2) * 64 + c2 * 4 + p] = v.z;
      As[(km * 4 + 3) * 64 + c2 * 4 + p] = v.w;
    }
#pragma unroll
    for (int i = 0; i < 4; ++i) {
      int f = tid + i * 256;
      int kr = f >> 4, nq = f & 15;
      float4 v = *(const float4*)&mem[(size_t)(k0 + kr) * 1024 + n0 + nq * 4];
      ((float4*)Bs)[kr * 16 + ((nq ^ (kr >> 2)) & 15)] = v;
    }
    __syncthreads();
#pragma unroll 8
    for (int kk = 0; kk < 64; ++kk) {
      int sw = kk >> 2;
      float4 a4 = As4[kk * 16 + ((ridx ^ sw) & 15)];
      float4 b4 = Bs4[kk * 16 + ((cidx ^ sw) & 15)];
      float av[4] = {a4.x, a4.y, a4.z, a4.w};
      float bv[4] = {b4.x, b4.y, b4.z, b4.w};
#pragma unroll
      for (int i = 0; i < 4; ++i)
#pragma unroll
        for (int j = 0; j < 4; ++j) acc[i][j] += av[i] * bv[j];
    }
    __syncthreads();
  }
  int gcol = n0 + cidx * 4;
  float* P = Pc + (size_t)blockIdx.y * 64 * 1024;
#pragma unroll
  for (int i = 0; i < 4; ++i) {
    int row = ridx * 4 + i;
    *(float4*)&P[(size_t)row * 1024 + gcol] =
        make_float4(acc[i][0], acc[i][1], acc[i][2], acc[i][3]);
  }
}

// ---------------- dual reduce: y selects (P, bias, out); bf16 copy of o1 (hw) ----------------
__global__ __launch_bounds__(256) void k_reduce_dual(
    const float* __restrict__ P0, const float* __restrict__ P1, int S, int N,
    const float* __restrict__ ba0, const float* __restrict__ ba1,
    float* __restrict__ o0, float* __restrict__ o1, int relu,
    unsigned short* __restrict__ hwb_out) {
  const float* P = blockIdx.y ? P1 : P0;
  const float* bias = blockIdx.y ? ba1 : ba0;
  float* out = blockIdx.y ? o1 : o0;
  int q = blockIdx.x * 256 + threadIdx.x;
  int total = 64 * N / 4;
  if (q >= total) return;
  int e0 = q * 4;
  int col = e0 % N;
  float4 v = make_float4(0, 0, 0, 0);
  for (int s = 0; s < S; ++s) {
    float4 p = *(const float4*)&P[(size_t)s * 64 * N + e0];
    v.x += p.x; v.y += p.y; v.z += p.z; v.w += p.w;
  }
  if (bias) {
    float4 b = *(const float4*)&bias[col];
    v.x += b.x; v.y += b.y; v.z += b.z; v.w += b.w;
  }
  if (relu) {
    v.x = fmaxf(v.x, 0.f); v.y = fmaxf(v.y, 0.f);
    v.z = fmaxf(v.z, 0.f); v.w = fmaxf(v.w, 0.f);
  }
  *(float4*)&out[e0] = v;
  if (blockIdx.y == 1 && hwb_out) {
    unsigned pk0 = (unsigned)f2bf(v.x) | ((unsigned)f2bf(v.y) << 16);
    unsigned pk1 = (unsigned)f2bf(v.z) | ((unsigned)f2bf(v.w) << 16);
    *(uint2*)&hwb_out[e0] = make_uint2(pk0, pk1);
  }
}

// ---------------- split-K reduce + bias, float4 (word logits fallback) ----------------
__global__ __launch_bounds__(256) void k_reduce4(
    const float* __restrict__ P, int S, int N,
    const float* __restrict__ bias, float* __restrict__ out) {
  int q = blockIdx.x * 256 + threadIdx.x;
  int total = 64 * N / 4;
  if (q >= total) return;
  int e0 = q * 4;
  int col = e0 % N;
  float4 v = make_float4(0, 0, 0, 0);
  for (int s = 0; s < S; ++s) {
    float4 p = *(const float4*)&P[(size_t)s * 64 * N + e0];
    v.x += p.x; v.y += p.y; v.z += p.z; v.w += p.w;
  }
  float4 b = *(const float4*)&bias[col];
  v.x += b.x; v.y += b.y; v.z += b.z; v.w += b.w;
  *(float4*)&out[e0] = v;
}

// ---------------- persistent recurrence (R10-proven; hs[2] double buffer, 1 barrier) ----
__global__ __launch_bounds__(256, 1) void k_recur(
    const float* __restrict__ Whh_term, const float* __restrict__ Whh_act,
    const float* __restrict__ Pxg_term, const float* __restrict__ Pxg_act,
    const float* __restrict__ bih_t, const float* __restrict__ bhh_t,
    const float* __restrict__ bih_a, const float* __restrict__ bhh_a,
    float* __restrict__ fin, u64* __restrict__ htag) {
  __shared__ float hs[2][32 * 36];    // double buffer, pad-36
  __shared__ float xgs[63 * 32];
  int b = blockIdx.x, tid = threadIdx.x;
  int lstm = b >> 7, k0 = (b & 127) * 8;
  const float* Whh = lstm ? Whh_act : Whh_term;
  const float* Pxg = lstm ? Pxg_act : Pxg_term;
  const float* bih = lstm ? bih_a : bih_t;
  const float* bhh = lstm ? bhh_a : bhh_t;
  int d = tid >> 5, p = tid & 31;

  float wreg[128];
#pragma unroll
  for (int g = 0; g < 4; ++g) {
    const float* wrow = Whh + (size_t)(g * 1024 + k0 + d) * 1024 + p * 32;
#pragma unroll
    for (int i = 0; i < 32; i += 4) {
      float4 v = *(const float4*)(wrow + i);
      wreg[g * 32 + i]     = v.x; wreg[g * 32 + i + 1] = v.y;
      wreg[g * 32 + i + 2] = v.z; wreg[g * 32 + i + 3] = v.w;
    }
  }
#pragma unroll
  for (int i = 0; i < 128; ++i) asm volatile("" : "+v"(wreg[i]));

  for (int i = tid; i < 63 * 32; i += 256) {
    int rr = i & 31, t2 = i >> 5;
    int row2 = (rr >> 3) * 1024 + k0 + (rr & 7);
    xgs[i] = Pxg[(size_t)t2 * 4096 + row2] + Pxg[262144 + (size_t)t2 * 4096 + row2] +
             bih[row2] + bhh[row2];
  }
  float c_loc = 0.f;

  for (int t = 0; t < 63; ++t) {
    float* hb = hs[t & 1];
    if (t > 0) {
      const u64* src = htag + (size_t)t * 2048 + lstm * 1024;
      u64 v0 = __hip_atomic_load(&src[tid], __ATOMIC_RELAXED, __HIP_MEMORY_SCOPE_AGENT);
      u64 v1 = __hip_atomic_load(&src[tid + 256], __ATOMIC_RELAXED, __HIP_MEMORY_SCOPE_AGENT);
      u64 v2 = __hip_atomic_load(&src[tid + 512], __ATOMIC_RELAXED, __HIP_MEMORY_SCOPE_AGENT);
      u64 v3 = __hip_atomic_load(&src[tid + 768], __ATOMIC_RELAXED, __HIP_MEMORY_SCOPE_AGENT);
      while ((unsigned)(v0 >> 32) != (unsigned)t) {
        __builtin_amdgcn_s_sleep(1);
        v0 = __hip_atomic_load(&src[tid], __ATOMIC_RELAXED, __HIP_MEMORY_SCOPE_AGENT);
      }
      while ((unsigned)(v1 >> 32) != (unsigned)t) {
        __builtin_amdgcn_s_sleep(1);
        v1 = __hip_atomic_load(&src[tid + 256], __ATOMIC_RELAXED, __HIP_MEMORY_SCOPE_AGENT);
      }
      while ((unsigned)(v2 >> 32) != (unsigned)t) {
        __builtin_amdgcn_s_sleep(1);
        v2 = __hip_atomic_load(&src[tid + 512], __ATOMIC_RELAXED, __HIP_MEMORY_SCOPE_AGENT);
      }
      while ((unsigned)(v3 >> 32) != (unsigned)t) {
        __builtin_amdgcn_s_sleep(1);
        v3 = __hip_atomic_load(&src[tid + 768], __ATOMIC_RELAXED, __HIP_MEMORY_SCOPE_AGENT);
      }
      hb[((tid) >> 5) * 36 + (tid & 31)]         = __uint_as_float((unsigned)v0);
      hb[((tid + 256) >> 5) * 36 + (tid & 31)]   = __uint_as_float((unsigned)v1);
      hb[((tid + 512) >> 5) * 36 + (tid & 31)]   = __uint_as_float((unsigned)v2);
      hb[((tid + 768) >> 5) * 36 + (tid & 31)]   = __uint_as_float((unsigned)v3);
    } else {
#pragma unroll
      for (int j = 0; j < 4; ++j) {
        int idx = tid + j * 256;
        hb[(idx >> 5) * 36 + (idx & 31)] = 0.f;
      }
    }
    __syncthreads();   // single barrier per step (hs[2] dbuf makes it sufficient)

    const float* hp = hb + p * 36;
    float s0 = 0.f, s1 = 0.f, s2 = 0.f, s3 = 0.f;
#pragma unroll
    for (int i = 0; i < 32; i += 4) {
      float4 hv = *(const float4*)&hp[i];
      s0 += wreg[i] * hv.x + wreg[i + 1] * hv.y + wreg[i + 2] * hv.z + wreg[i + 3] * hv.w;
      s1 += wreg[32 + i] * hv.x + wreg[33 + i] * hv.y + wreg[34 + i] * hv.z + wreg[35 + i] * hv.w;
      s2 += wreg[64 + i] * hv.x + wreg[65 + i] * hv.y + wreg[66 + i] * hv.z + wreg[67 + i] * hv.w;
      s3 += wreg[96 + i] * hv.x + wreg[97 + i] * hv.y + wreg[98 + i] * hv.z + wreg[99 + i] * hv.w;
    }
#pragma unroll
    for (int m = 1; m <= 16; m <<= 1) {
      s0 += __shfl_xor(s0, m); s1 += __shfl_xor(s1, m);
      s2 += __shfl_xor(s2, m); s3 += __shfl_xor(s3, m);
    }
    if (p == 0) {
      float gi = s0 + xgs[t * 32 + d];
      float gf = s1 + xgs[t * 32 + 8 + d];
      float gg = s2 + xgs[t * 32 + 16 + d];
      float go = s3 + xgs[t * 32 + 24 + d];
      float c2 = sigmf(gf) * c_loc + sigmf(gi) * tanhf(gg);
      float h2 = sigmf(go) * tanhf(c2);
      c_loc = c2;
      fin[(size_t)(t + 1) * 4096 + lstm * 1024 + k0 + d] = h2;  // for tail kernels
      __hip_atomic_store(&htag[(size_t)(t + 1) * 2048 + lstm * 1024 + k0 + d],
                         (((u64)(t + 1)) << 32) | (u64)__float_as_uint(h2),
                         __ATOMIC_RELAXED, __HIP_MEMORY_SCOPE_AGENT);
    }
  }
}

// ---------------- word logits via bf16 MFMA, fp32 weights converted in-register ------
// Per wave: 64x16 output; A from hwb (bf16, L2-resident), B from Ww2 fp32 (123 MB,
// read once, coalesced: lane-quads {x,x+16,x+32,x+48} cover 128B of one row).
__global__ __launch_bounds__(256) void k_word_mfma(
    const unsigned short* __restrict__ hwb, const float* __restrict__ Ww2,
    const float* __restrict__ bw2, float* __restrict__ outw) {
  int tid = threadIdx.x;
  int wv = tid >> 6, lane = tid & 63;
  int col = blockIdx.x * 64 + wv * 16 + (lane & 15);
  int colr = col < VW ? col : VW - 1;
  int kg = (lane >> 4) * 8;
  const float* brow = Ww2 + (size_t)colr * 1024 + kg;
  const unsigned short* arow = hwb + (size_t)(lane & 15) * 1024 + kg;
  f32x4 acc0 = {0.f, 0.f, 0.f, 0.f}, acc1 = acc0, acc2 = acc0, acc3 = acc0;

  short8 bf = ldcvt8(brow);
  short8 a0 = *(const short8*)(arow);
  short8 a1 = *(const short8*)(arow + 16 * 1024);
  short8 a2 = *(const short8*)(arow + 32 * 1024);
  short8 a3 = *(const short8*)(arow + 48 * 1024);
  for (int k0 = 0; k0 < 992; k0 += 32) {
    short8 bf_n = ldcvt8(brow + k0 + 32);
    short8 a0n = *(const short8*)(arow + k0 + 32);
    short8 a1n = *(const short8*)(arow + 16 * 1024 + k0 + 32);
    short8 a2n = *(const short8*)(arow + 32 * 1024 + k0 + 32);
    short8 a3n = *(const short8*)(arow + 48 * 1024 + k0 + 32);
    acc0 = __builtin_amdgcn_mfma_f32_16x16x32_bf16(a0, bf, acc0, 0, 0, 0);
    acc1 = __builtin_amdgcn_mfma_f32_16x16x32_bf16(a1, bf, acc1, 0, 0, 0);
    acc2 = __builtin_amdgcn_mfma_f32_16x16x32_bf16(a2, bf, acc2, 0, 0, 0);
    acc3 = __builtin_amdgcn_mfma_f32_16x16x32_bf16(a3, bf, acc3, 0, 0, 0);
    bf = bf_n; a0 = a0n; a1 = a1n; a2 = a2n; a3 = a3n;
  }
  acc0 = __builtin_amdgcn_mfma_f32_16x16x32_bf16(a0, bf, acc0, 0, 0, 0);
  acc1 = __builtin_amdgcn_mfma_f32_16x16x32_bf16(a1, bf, acc1, 0, 0, 0);
  acc2 = __builtin_amdgcn_mfma_f32_16x16x32_bf16(a2, bf, acc2, 0, 0, 0);
  acc3 = __builtin_amdgcn_mfma_f32_16x16x32_bf16(a3, bf, acc3, 0, 0, 0);

  if (col < VW) {
    float bias = bw2[col];
    int r0 = (lane >> 4) * 4;
#pragma unroll
    for (int j = 0; j < 4; ++j) {
      outw[(size_t)(r0 + j) * VW + col]      = acc0[j] + bias;
      outw[(size_t)(16 + r0 + j) * VW + col] = acc1[j] + bias;
      outw[(size_t)(32 + r0 + j) * VW + col] = acc2[j] + bias;
      outw[(size_t)(48 + r0 + j) * VW + col] = acc3[j] + bias;
    }
  }
}

// ---------------- word GEMM fallback: 64x128 tile fp32 (R10-proven) ----------------
__global__ __launch_bounds__(256) void k_wordN(
    const float* __restrict__ hw, const float* __restrict__ Ww2,
    const float* __restrict__ bw2, float* __restrict__ Pword,
    float* __restrict__ outw) {
  __shared__ __align__(16) float As[64 * 64];
  __shared__ __align__(16) float Bs0[64 * 64];
  __shared__ __align__(16) float Bs1[64 * 64];
  const float4* As4  = (const float4*)As;
  const float4* Bs04 = (const float4*)Bs0;
  const float4* Bs14 = (const float4*)Bs1;
  int tid = threadIdx.x;
  int cidx = tid & 15;
  int ridx = tid >> 4;
  int n0 = blockIdx.x * 128;
  int splitk = gridDim.y;
  int klen = 1024 / splitk;
  int kbeg = blockIdx.y * klen;
  float acc0[4][4] = {}, acc1[4][4] = {};

  for (int k0 = kbeg; k0 < kbeg + klen; k0 += 64) {
#pragma unroll
    for (int i = 0; i < 4; ++i) {
      int f = tid + i * 256;
      int rr = f >> 4, km = f & 15;
      float4 v = *(const float4*)&hw[(size_t)rr * 1024 + k0 + km * 4];
      int c2 = ((rr >> 2) ^ km) & 15, p = rr & 3;
      As[(km * 4 + 0) * 64 + c2 * 4 + p] = v.x;
      As[(km * 4 + 1) * 64 + c2 * 4 + p] = v.y;
      As[(km * 4 + 2) * 64 + c2 * 4 + p] = v.z;
      As[(km * 4 + 3) * 64 + c2 * 4 + p] = v.w;
    }
#pragma unroll
    for (int h = 0; h < 2; ++h) {
      float* Bsh = h ? Bs1 : Bs0;
#pragma unroll
      for (int i = 0; i < 4; ++i) {
        int f = tid + i * 256;
        int nn = f >> 4, km = f & 15;
        int gn = n0 + h * 64 + nn;
        float4 v = make_float4(0.f, 0.f, 0.f, 0.f);
        if (gn < VW) v = *(const float4*)&Ww2[(size_t)gn * 1024 + k0 + km * 4];
        int c2 = ((nn >> 2) ^ km) & 15, p = nn & 3;
        Bsh[(km * 4 + 0) * 64 + c2 * 4 + p] = v.x;
        Bsh[(km * 4 + 1) * 64 + c2 * 4 + p] = v.y;
        Bsh[(km * 4 + 2) * 64 + c2 * 4 + p] = v.z;
        Bsh[(km * 4 + 3) * 64 + c2 * 4 + p] = v.w;
      }
    }
    __syncthreads();
#pragma unroll 4
    for (int kk = 0; kk < 64; ++kk) {
      int sw = kk >> 2;
      float4 a4 = As4[kk * 16 + ((ridx ^ sw) & 15)];
      float4 b0 = Bs04[kk * 16 + ((cidx ^ sw) & 15)];
      float4 b1 = Bs14[kk * 16 + ((cidx ^ sw) & 15)];
      float av[4] = {a4.x, a4.y, a4.z, a4.w};
      float b0v[4] = {b0.x, b0.y, b0.z, b0.w};
      float b1v[4] = {b1.x, b1.y, b1.z, b1.w};
#pragma unroll
      for (int i = 0; i < 4; ++i)
#pragma unroll
        for (int j = 0; j < 4; ++j) {
          acc0[i][j] += av[i] * b0v[j];
          acc1[i][j] += av[i] * b1v[j];
        }
    }
    __syncthreads();
  }

  int g0 = n0 + cidx * 4;
  int g1 = n0 + 64 + cidx * 4;
  if (splitk > 1) {
    float* P = Pword + (size_t)blockIdx.y * 64 * VW;
#pragma unroll
    for (int i = 0; i < 4; ++i) {
      int row = ridx * 4 + i;
      if (g0 < VW)
        *(float4*)&P[(size_t)row * VW + g0] =
            make_float4(acc0[i][0], acc0[i][1], acc0[i][2], acc0[i][3]);
      if (g1 < VW)
        *(float4*)&P[(size_t)row * VW + g1] =
            make_float4(acc1[i][0], acc1[i][1], acc1[i][2], acc1[i][3]);
    }
  } else {
#pragma unroll
    for (int i = 0; i < 4; ++i) {
      int row = ridx * 4 + i;
      if (g0 < VW) {
        float4 b = *(const float4*)&bw2[g0];
        *(float4*)&outw[(size_t)row * VW + g0] =
            make_float4(acc0[i][0] + b.x, acc0[i][1] + b.y,
                        acc0[i][2] + b.z, acc0[i][3] + b.w);
      }
      if (g1 < VW) {
        float4 b = *(const float4*)&bw2[g1];
        *(float4*)&outw[(size_t)row * VW + g1] =
            make_float4(acc1[i][0] + b.x, acc1[i][1] + b.y,
                        acc1[i][2] + b.z, acc1[i][3] + b.w);
      }
    }
  }
}

// ---------------- action logits: [64,30] = ha @ Wa2^T + ba2 ----------------
__global__ __launch_bounds__(256) void k_actlog(
    const float* __restrict__ ha, const float* __restrict__ Wa2,
    const float* __restrict__ ba2, float* __restrict__ out) {
  int t = blockIdx.x, tid = threadIdx.x;
  int v = tid >> 3, p = tid & 7;
  float sum = 0.f;
  if (v < VA) {
    const float* a  = ha + (size_t)t * 1024 + p * 128;
    const float* wr = Wa2 + (size_t)v * 1024 + p * 128;
#pragma unroll 8
    for (int i = 0; i < 128; i += 4) {
      float4 av = *(const float4*)(a + i);
      float4 wv = *(const float4*)(wr + i);
      sum += av.x * wv.x + av.y * wv.y + av.z * wv.z + av.w * wv.w;
    }
  }
  sum += __shfl_xor(sum, 1);
  sum += __shfl_xor(sum, 2);
  sum += __shfl_xor(sum, 4);
  if (p == 0 && v < VA) out[(size_t)t * VA + v] = sum + ba2[v];
}

extern "C" void kernel_launch(void* const* d_in, const int* in_sizes, int n_in,
                              void* d_out, int out_size, void* d_ws, size_t ws_size,
                              hipStream_t stream) {
  const float* memory   = (const float*)d_in[0];
  const int*   actions  = (const int*)d_in[1];
  const int*   words    = (const int*)d_in[2];
  const float* term_Wih = (const float*)d_in[3];
  const float* term_Whh = (const float*)d_in[4];
  const float* term_bih = (const float*)d_in[5];
  const float* term_bhh = (const float*)d_in[6];
  const float* act_Wih  = (const float*)d_in[7];
  const float* act_Whh  = (const float*)d_in[8];
  const float* act_bih  = (const float*)d_in[9];
  const float* act_bhh  = (const float*)d_in[10];
  const float* Wq  = (const float*)d_in[11];
  const float* bq  = (const float*)d_in[12];
  const float* Wa1 = (const float*)d_in[13];
  const float* ba1 = (const float*)d_in[14];
  const float* Wa2 = (const float*)d_in[15];
  const float* ba2 = (const float*)d_in[16];
  const float* Ww1 = (const float*)d_in[17];
  const float* bw1 = (const float*)d_in[18];
  const float* Ww2 = (const float*)d_in[19];
  const float* bw2 = (const float*)d_in[20];
  const float* act_emb  = (const float*)d_in[21];
  const float* word_emb = (const float*)d_in[22];
  float* out = (float*)d_out;

  // workspace layout (floats), phase-overlapped:
  float* w      = (float*)d_ws;
  float* fin    = w;
  u64*   htag   = (u64*)(w + 262144);
  float* Pa     = (float*)htag;
  float* X_term = w + 524288;
  float* X_act  = w + 589824;
  float* Pc     = X_term;
  float* ha     = w + 655360;
  float* hw     = w + 720896;
  float* arena  = w + 786432;
  unsigned short* hwb = (unsigned short*)(arena + 1048576);  // 64*1024 bf16

  size_t need_mfma = (size_t)(786432 + 1048576 + 32768) * 4;
  bool mfmaw = ws_size >= need_mfma;
  int wsplit = (ws_size >= (size_t)(786432 + 4ull * 64 * VW) * 4) ? 4
             : (ws_size >= (size_t)(786432 + 2ull * 64 * VW) * 4) ? 2 : 1;

  k_init<<<129, 256, 0, stream>>>(actions, words, act_emb, word_emb,
                                  X_term, X_act, fin, htag);

  // xg pair partials: Pxg = X @ Wih^T   (N=4096, K=1024, splitk=2, z=2)
  k_gemm_dual<<<dim3(64, 2, 2), 256, 0, stream>>>(
      X_term, X_act, 1024, term_Wih, act_Wih, 1024, 4096, 1024,
      arena, arena + 524288, nullptr, 1 << 30);

  // 63 recurrence steps (xg reduce fused into xgs preload)
  k_recur<<<256, 256, 0, stream>>>(term_Whh, act_Whh, arena, arena + 524288,
                                   term_bih, term_bhh, act_bih, act_bhh, fin, htag);

  // q partials: Pq = states @ Wq^T   (K=3072, N=1024, splitk=8) -> arena
  k_gemm64<<<dim3(16, 8), 256, 0, stream>>>(fin, 4096, Wq, 3072, 1024, 3072, arena);

  // attn partials (q reduce + bq fused into A-staging)
  k_attn<<<dim3(8, 8), 256, 0, stream>>>(arena, bq, memory, Pa);

  // ctx partials (attn reduce fused into A-staging)
  k_ctx<<<dim3(16, 2), 256, 0, stream>>>(Pa, memory, Pc);

  // ha/hw partials: A = [fin | sum2(Pc)] (ctx reduce fused), splitk=8, z=2
  k_gemm_dual<<<dim3(16, 8, 2), 256, 0, stream>>>(
      fin, fin, 4096, Wa1, Ww1, 4096, 1024, 4096,
      arena, arena + 524288, Pc, 3072);
  k_reduce_dual<<<dim3(64, 2), 256, 0, stream>>>(
      arena, arena + 524288, 8, 1024, ba1, bw1, ha, hw, 1,
      mfmaw ? hwb : nullptr);

  // act logits (separate, proven)
  k_actlog<<<64, 256, 0, stream>>>(ha, Wa2, ba2, out);

  // word logits
  if (mfmaw) {
    k_word_mfma<<<469, 256, 0, stream>>>(hwb, Ww2, bw2, out + 1920);
  } else {
    k_wordN<<<dim3(235, wsplit), 256, 0, stream>>>(hw, Ww2, bw2, arena, out + 1920);
    if (wsplit > 1)
      k_reduce4<<<1875, 256, 0, stream>>>(arena, wsplit, VW, bw2, out + 1920);
  }
}